// Round 6
// baseline (95.412 us; speedup 1.0000x reference)
//
#include <hip/hip_runtime.h>

typedef __attribute__((ext_vector_type(8))) short s8v;
typedef __attribute__((ext_vector_type(4))) short s4v;
typedef __attribute__((ext_vector_type(4))) float fx4;
typedef __attribute__((ext_vector_type(4))) unsigned int u32x4;
typedef unsigned short u16;
typedef unsigned int u32;
typedef unsigned char u8;

#define QK_SCALE 0.1803368801111204f  /* 0.125 * log2(e) */

#if __has_builtin(__builtin_amdgcn_exp2f)
#define EXP2(x) __builtin_amdgcn_exp2f(x)
#else
#define EXP2(x) exp2f(x)
#endif

static __device__ __forceinline__ u16 f2bf(float f) {
    u32 u = __float_as_uint(f);
    u += 0x7fffu + ((u >> 16) & 1u);
    return (u16)(u >> 16);
}
static __device__ __forceinline__ float bf2f(u16 h) {
    return __uint_as_float(((u32)h) << 16);
}

static __device__ __forceinline__ fx4 mfma16(s4v a, s4v b, fx4 c) {
#if __has_builtin(__builtin_amdgcn_mfma_f32_16x16x16bf16_1k)
    return __builtin_amdgcn_mfma_f32_16x16x16bf16_1k(a, b, c, 0, 0, 0);
#else
    asm("v_mfma_f32_16x16x16_bf16 %0, %1, %2, %3" : "=v"(c) : "v"(a), "v"(b), "v"(c));
    return c;
#endif
}

// ---------------- init: static V^T rows d=8 (ones) and 9..15 (zeros) for Vt0,Vt1 ----------------
// Region = one (buf,bh,kg) tile: 512B; static part at +256B: 64 words (8 ones, 56 zero).
__global__ __launch_bounds__(256) void init_vt_kernel(u32* __restrict__ VtBoth)
{
    const int idx = blockIdx.x * 256 + threadIdx.x;   // 2*32*128*64 = 524288
    const int region = idx >> 6, word = idx & 63;
    VtBoth[region * 128 + 64 + word] = (word < 8) ? 0x3f803f80u : 0u;
}

// ---------------- K1: qkv proj -> Qh (scaled hi/lo), Kh (hi/lo), Vt (transposed bf16) ----------------
__global__ __launch_bounds__(192) void qkv_proj_kernel(
    const float* __restrict__ X, const float* __restrict__ W,
    const float* __restrict__ bias,
    u16* __restrict__ Qh, u16* __restrict__ Kh, u16* __restrict__ Vt)
{
    __shared__ __align__(16) float xsT[64 * 12];
    const int row0 = blockIdx.x * 8;
    const int t = threadIdx.x;
    if (t < 64) {
        #pragma unroll
        for (int r = 0; r < 8; ++r)
            xsT[t * 12 + r] = X[(size_t)(row0 + r) * 64 + t];
    }
    __syncthreads();
    const int j = t;
    const float bj = bias[j];
    float acc[8];
    #pragma unroll
    for (int r = 0; r < 8; ++r) acc[r] = bj;
    #pragma unroll 4
    for (int k = 0; k < 64; ++k) {
        const float w = W[k * 192 + j];
        const float4 x0 = *(const float4*)&xsT[k * 12];
        const float4 x1 = *(const float4*)&xsT[k * 12 + 4];
        acc[0] = fmaf(x0.x, w, acc[0]);
        acc[1] = fmaf(x0.y, w, acc[1]);
        acc[2] = fmaf(x0.z, w, acc[2]);
        acc[3] = fmaf(x0.w, w, acc[3]);
        acc[4] = fmaf(x1.x, w, acc[4]);
        acc[5] = fmaf(x1.y, w, acc[5]);
        acc[6] = fmaf(x1.z, w, acc[6]);
        acc[7] = fmaf(x1.w, w, acc[7]);
    }
    const int c = j & 63;
    const int h = c >> 3, d = c & 7;
    #pragma unroll
    for (int r = 0; r < 8; ++r) {
        const int R = row0 + r;
        const int bi = R >> 11, i = R & 2047;
        const int bh = bi * 8 + h;
        const float v = acc[r];
        if (j < 64) {
            const float qs = v * QK_SCALE;
            const u16 hh = f2bf(qs);
            const u16 ll = f2bf(qs - bf2f(hh));
            u16* qp = Qh + ((size_t)(bh * 2048 + i)) * 16 + d;
            qp[0] = hh; qp[8] = ll;
        } else if (j < 128) {
            const u16 hh = f2bf(v);
            const u16 ll = f2bf(v - bf2f(hh));
            u16* kp = Kh + ((size_t)(bh * 128 + (i >> 4)) * 16 + (i & 15)) * 16 + d;
            kp[0] = hh; kp[8] = ll;
        } else {
            Vt[((size_t)(bh * 128 + (i >> 4)) * 16 + d) * 16 + (i & 15)] = f2bf(v);
        }
    }
}

// ---------------- MFMA flash attention, split-K=2, preconverted operands ----------------
// grid (bh=32, qt=32, sp=2), block 256 = 4 waves, 16 q per wave, 1024 keys per block.
// LDS chunk (4KB x2 dbuf): [0,2KB) K: 4 kg x [16 key][hi8|lo8] ; [2KB,4KB) V: 4 kg x [16 d][16 key]
// QK: mfma_16x16x32: A lane(key=l&15, g=l>>4) slots 8g.. = K hi(g even)/lo(g odd);
//     B = Q [qhi,qhi,qlo,qlo] -> full (Khi+Klo)x(Qhi+Qlo). C: col=q=l&15, row=key=4g+r.
// P=exp2(S) -> SOFTWARE f2bf (round-2-proven; no inline asm -> compiler manages all
// TRANS/VALU hazards) = B-frag of 16x16x16 (k=4g+j). A_V rows: d=0..7 V^T, 8=ones.
// Staging: per-lane global_load_dwordx4 -> reg -> ds_write_b128, double buffer,
// ONE __syncthreads per chunk.
__global__ __launch_bounds__(256) void attn_mfma2_kernel(
    const u16* __restrict__ Qh, const u8* __restrict__ Khb,
    const u8* __restrict__ Vtb, float* __restrict__ Part)
{
    __shared__ __align__(16) u8 smem[2 * 4096];
    const int bh = blockIdx.x, qt = blockIdx.y, sp = blockIdx.z;
    const int tid = threadIdx.x, w = tid >> 6, l = tid & 63;
    const int g = l >> 4, ql = l & 15;
    const int qglob = qt * 64 + w * 16 + ql;

    const s8v bq = *(const s8v*)(Qh + ((size_t)(bh * 2048 + qglob)) * 16 + (g >> 1) * 8);

    // staging source: waves 0,1 cover K halves; waves 2,3 cover V halves (1KB per wave, linear)
    const u8* gsrc = ((w < 2) ? Khb : Vtb) + (size_t)bh * 65536 + sp * 32768
                     + (w & 1) * 1024 + l * 16;
    const u32 dstoff = (u32)((w < 2 ? 0 : 2048) + (w & 1) * 1024 + l * 16);

    fx4 accO = {0.f, 0.f, 0.f, 0.f};
    const fx4 zf = {0.f, 0.f, 0.f, 0.f};

    u32x4 reg = *(const u32x4*)gsrc;   // chunk 0

    #pragma unroll 1
    for (int t = 0; t < 16; ++t) {
        const u32 boff = (u32)(t & 1) * 4096u;
        *(u32x4*)(smem + boff + dstoff) = reg;          // stage chunk t
        if (t < 15)
            reg = *(const u32x4*)(gsrc + (t + 1) * 2048);  // prefetch t+1 (overlaps compute)
        __syncthreads();                                 // staged data visible to all
        const u8* Kb = smem + boff;
        const u8* Vb = Kb + 2048;
        const u8* akp = Kb + ql * 32 + (g & 1) * 16;
        const u8* avp = Vb + ql * 32 + g * 8;
        #pragma unroll
        for (int kg = 0; kg < 4; ++kg) {
            const s8v ak = *(const s8v*)(akp + kg * 512);
            fx4 s = __builtin_amdgcn_mfma_f32_16x16x32_bf16(ak, bq, zf, 0, 0, 0);
            const float p0 = EXP2(s[0]), p1 = EXP2(s[1]);
            const float p2 = EXP2(s[2]), p3 = EXP2(s[3]);
            s4v bp;
            bp[0] = (short)f2bf(p0); bp[1] = (short)f2bf(p1);
            bp[2] = (short)f2bf(p2); bp[3] = (short)f2bf(p3);
            const s4v av = *(const s4v*)(avp + kg * 512);
            accO = mfma16(av, bp, accO);
        }
        // buffer boff is next overwritten at t+2, after t+1's __syncthreads; our
        // ds_reads are drained by our own arrival at that barrier.
    }

    // partials: rows d = 4g+r for g<2 ; denominator = row 8 (g==2, reg 0)
    float* pp = Part + ((size_t)(bh * 2048 + qglob)) * 24 + sp * 12;
    if (g < 2) {
        const float4 o = {accO[0], accO[1], accO[2], accO[3]};
        *(float4*)(pp + g * 4) = o;
    } else if (g == 2) {
        pp[8] = accO[0];
    }
}

// ---------------- combine split partials ----------------
__global__ __launch_bounds__(256) void attn_combine2_kernel(
    const float* __restrict__ Part, float* __restrict__ M)
{
    const int idx = blockIdx.x * 256 + threadIdx.x;   // 65536 = bh*2048 + q
    const float* pp = Part + (size_t)idx * 24;
    const float inv = 1.0f / (pp[8] + pp[20]);
    float o[8];
    #pragma unroll
    for (int d = 0; d < 8; ++d) o[d] = (pp[d] + pp[12 + d]) * inv;
    const int bh = idx >> 11, q = idx & 2047;
    const int b = bh >> 3, h = bh & 7;
    float* op = M + ((size_t)(b * 2048 + q)) * 64 + h * 8;
    const float4 o0 = {o[0], o[1], o[2], o[3]};
    const float4 o1 = {o[4], o[5], o[6], o[7]};
    *(float4*)op = o0;
    *(float4*)(op + 4) = o1;
}

// ---------------- proj64: mode 0 -> stage-2 Qh/Kh/Vt buffers; mode 1 -> plain f32 out ----------------
// q1 reshape: p-row rr, col c -> bh=bi*8+(rr>>8), key=(rr&255)*8+(c>>3), d=c&7
__global__ __launch_bounds__(64) void proj64_kernel(
    const float* __restrict__ X, const float* __restrict__ W,
    const float* __restrict__ bias,
    u16* __restrict__ Qh, u16* __restrict__ Kh, u16* __restrict__ Vt,
    float* __restrict__ Out, int mode)
{
    __shared__ __align__(16) float xsT[64 * 12];
    const int row0 = blockIdx.x * 8;
    const int c = threadIdx.x;
    #pragma unroll
    for (int r = 0; r < 8; ++r)
        xsT[c * 12 + r] = X[(size_t)(row0 + r) * 64 + c];
    __syncthreads();
    const float bc = bias[c];
    float acc[8];
    #pragma unroll
    for (int r = 0; r < 8; ++r) acc[r] = bc;
    #pragma unroll 4
    for (int k = 0; k < 64; ++k) {
        const float w = W[k * 64 + c];
        const float4 x0 = *(const float4*)&xsT[k * 12];
        const float4 x1 = *(const float4*)&xsT[k * 12 + 4];
        acc[0] = fmaf(x0.x, w, acc[0]);
        acc[1] = fmaf(x0.y, w, acc[1]);
        acc[2] = fmaf(x0.z, w, acc[2]);
        acc[3] = fmaf(x0.w, w, acc[3]);
        acc[4] = fmaf(x1.x, w, acc[4]);
        acc[5] = fmaf(x1.y, w, acc[5]);
        acc[6] = fmaf(x1.z, w, acc[6]);
        acc[7] = fmaf(x1.w, w, acc[7]);
    }
    if (mode == 0) {
        #pragma unroll
        for (int r = 0; r < 8; ++r) {
            const int R = row0 + r;
            const int bi = R >> 11, rr = R & 2047;
            const int bh = bi * 8 + (rr >> 8);
            const int key = (rr & 255) * 8 + (c >> 3);
            const int d = c & 7;
            const int kg = key >> 4, kr = key & 15;
            const float p = acc[r];
            const float qs = p * QK_SCALE;
            const u16 qh = f2bf(qs);
            const u16 qlo = f2bf(qs - bf2f(qh));
            const u16 kh = f2bf(p);
            const u16 kl = f2bf(p - bf2f(kh));
            u16* qp = Qh + ((size_t)(bh * 2048 + key)) * 16 + d;
            qp[0] = qh; qp[8] = qlo;
            u16* kp = Kh + ((size_t)(bh * 128 + kg) * 16 + kr) * 16 + d;
            kp[0] = kh; kp[8] = kl;
            Vt[((size_t)(bh * 128 + kg) * 16 + d) * 16 + kr] = f2bf(p);
        }
    } else {
        #pragma unroll
        for (int r = 0; r < 8; ++r)
            Out[(size_t)(row0 + r) * 64 + c] = acc[r];
    }
}

extern "C" void kernel_launch(void* const* d_in, const int* in_sizes, int n_in,
                              void* d_out, int out_size, void* d_ws, size_t ws_size,
                              hipStream_t stream) {
    const float* x    = (const float*)d_in[0];
    const float* Wqkv = (const float*)d_in[1];
    const float* bqkv = (const float*)d_in[2];
    const float* W1   = (const float*)d_in[3];
    const float* b1   = (const float*)d_in[4];
    float* out = (float*)d_out;
    u8* w8 = (u8*)d_ws;

    // byte layout (20 MiB total)
    u16*   Qh0  = (u16*)(w8);                       // 2 MiB
    u16*   Kh0  = (u16*)(w8 + (2u << 20));          // 2 MiB
    u16*   Vt0  = (u16*)(w8 + (4u << 20));          // 2 MiB
    u16*   Vt1  = (u16*)(w8 + (6u << 20));          // 2 MiB (adjacent to Vt0 for init)
    u16*   Qh1  = (u16*)(w8 + (8u << 20));          // 2 MiB
    u16*   Kh1  = (u16*)(w8 + (10u << 20));         // 2 MiB
    float* Part = (float*)(w8 + (12u << 20));       // 6 MiB
    float* M1   = (float*)(w8 + (18u << 20));       // 2 MiB
    float* M2   = (float*)(w8);                     // overlays Qh0 (dead by then)

    init_vt_kernel<<<2048, 256, 0, stream>>>((u32*)Vt0);  // covers Vt0 and Vt1
    qkv_proj_kernel<<<1024, 192, 0, stream>>>(x, Wqkv, bqkv, Qh0, Kh0, Vt0);
    attn_mfma2_kernel<<<dim3(32, 32, 2), 256, 0, stream>>>(Qh0, (const u8*)Kh0, (const u8*)Vt0, Part);
    attn_combine2_kernel<<<256, 256, 0, stream>>>(Part, M1);
    proj64_kernel<<<1024, 64, 0, stream>>>(M1, W1, b1, Qh1, Kh1, Vt1, nullptr, 0);
    attn_mfma2_kernel<<<dim3(32, 32, 2), 256, 0, stream>>>(Qh1, (const u8*)Kh1, (const u8*)Vt1, Part);
    attn_combine2_kernel<<<256, 256, 0, stream>>>(Part, M2);
    proj64_kernel<<<1024, 64, 0, stream>>>(M2, W1, b1, nullptr, nullptr, nullptr, out, 1);
}

// Round 7
// 86.270 us; speedup vs baseline: 1.1060x; 1.1060x over previous
//
#include <hip/hip_runtime.h>

typedef __attribute__((ext_vector_type(8))) short s8v;
typedef __attribute__((ext_vector_type(4))) short s4v;
typedef __attribute__((ext_vector_type(4))) float fx4;
typedef unsigned short u16;
typedef unsigned int u32;
typedef unsigned char u8;

#define QK_SCALE 0.1803368801111204f  /* 0.125 * log2(e) */

#if __has_builtin(__builtin_amdgcn_exp2f)
#define EXP2(x) __builtin_amdgcn_exp2f(x)
#else
#define EXP2(x) exp2f(x)
#endif

static __device__ __forceinline__ u16 f2bf(float f) {
    u32 u = __float_as_uint(f);
    u += 0x7fffu + ((u >> 16) & 1u);
    return (u16)(u >> 16);
}
static __device__ __forceinline__ float bf2f(u16 h) {
    return __uint_as_float(((u32)h) << 16);
}
// pack two non-negative f32 -> two bf16 (round-half-up) in one u32, via v_perm
static __device__ __forceinline__ int pack2bf(float a, float b) {
    const u32 ua = __float_as_uint(a) + 0x8000u;
    const u32 ub = __float_as_uint(b) + 0x8000u;
    return (int)__builtin_amdgcn_perm(ub, ua, 0x07060302u);
}

static __device__ __forceinline__ fx4 mfma16(s4v a, s4v b, fx4 c) {
#if __has_builtin(__builtin_amdgcn_mfma_f32_16x16x16bf16_1k)
    return __builtin_amdgcn_mfma_f32_16x16x16bf16_1k(a, b, c, 0, 0, 0);
#else
    asm("v_mfma_f32_16x16x16_bf16 %0, %1, %2, %3" : "=v"(c) : "v"(a), "v"(b), "v"(c));
    return c;
#endif
}

// ---------------- init: static V^T rows d=8 (ones) and 9..15 (zeros) for Vt0,Vt1 ----------------
__global__ __launch_bounds__(256) void init_vt_kernel(u32* __restrict__ VtBoth)
{
    const int idx = blockIdx.x * 256 + threadIdx.x;   // 2*32*128*64 = 524288
    const int region = idx >> 6, word = idx & 63;
    VtBoth[region * 128 + 64 + word] = (word < 8) ? 0x3f803f80u : 0u;
}

// ---------------- K1: qkv proj -> Qh (scaled hi/lo), Kh (hi/lo), Vt (transposed bf16) ----------------
__global__ __launch_bounds__(192) void qkv_proj_kernel(
    const float* __restrict__ X, const float* __restrict__ W,
    const float* __restrict__ bias,
    u16* __restrict__ Qh, u16* __restrict__ Kh, u16* __restrict__ Vt)
{
    __shared__ __align__(16) float xsT[64 * 12];
    const int row0 = blockIdx.x * 8;
    const int t = threadIdx.x;
    if (t < 64) {
        #pragma unroll
        for (int r = 0; r < 8; ++r)
            xsT[t * 12 + r] = X[(size_t)(row0 + r) * 64 + t];
    }
    __syncthreads();
    const int j = t;
    const float bj = bias[j];
    float acc[8];
    #pragma unroll
    for (int r = 0; r < 8; ++r) acc[r] = bj;
    #pragma unroll 4
    for (int k = 0; k < 64; ++k) {
        const float w = W[k * 192 + j];
        const float4 x0 = *(const float4*)&xsT[k * 12];
        const float4 x1 = *(const float4*)&xsT[k * 12 + 4];
        acc[0] = fmaf(x0.x, w, acc[0]);
        acc[1] = fmaf(x0.y, w, acc[1]);
        acc[2] = fmaf(x0.z, w, acc[2]);
        acc[3] = fmaf(x0.w, w, acc[3]);
        acc[4] = fmaf(x1.x, w, acc[4]);
        acc[5] = fmaf(x1.y, w, acc[5]);
        acc[6] = fmaf(x1.z, w, acc[6]);
        acc[7] = fmaf(x1.w, w, acc[7]);
    }
    const int c = j & 63;
    const int h = c >> 3, d = c & 7;
    #pragma unroll
    for (int r = 0; r < 8; ++r) {
        const int R = row0 + r;
        const int bi = R >> 11, i = R & 2047;
        const int bh = bi * 8 + h;
        const float v = acc[r];
        if (j < 64) {
            const float qs = v * QK_SCALE;
            const u16 hh = f2bf(qs);
            const u16 ll = f2bf(qs - bf2f(hh));
            u16* qp = Qh + ((size_t)(bh * 2048 + i)) * 16 + d;
            qp[0] = hh; qp[8] = ll;
        } else if (j < 128) {
            const u16 hh = f2bf(v);
            const u16 ll = f2bf(v - bf2f(hh));
            u16* kp = Kh + ((size_t)(bh * 128 + (i >> 4)) * 16 + (i & 15)) * 16 + d;
            kp[0] = hh; kp[8] = ll;
        } else {
            Vt[((size_t)(bh * 128 + (i >> 4)) * 16 + d) * 16 + (i & 15)] = f2bf(v);
        }
    }
}

// ---------------- MFMA attention v4: no LDS staging, wave = key-quarter ----------------
// grid (bh=32, qt=32, sp=2), block 256 = 4 waves. Block covers 64 q x 1024 keys;
// wave w covers keys [w*256, w*256+256) for ALL 64 q (4 Q-frags, 4 acc chains).
// ak/av loaded straight from global (Kh/Vt layouts == tile layouts; L1/L2-resident,
// identical across blocks of same bh). No barriers in main loop.
// QK: mfma_16x16x32: A lane(key=l&15, g=l>>4) slots = K hi(g even)/lo(g odd);
//     B = Q [qhi,qhi,qlo,qlo]. C: col=q=l&15, row=key=4g+r.
// P=exp2(S) -> pack2bf = B-frag of 16x16x16 (k=4g+j). A_V rows: d=0..7 V^T, 8=ones.
// Cross-wave key reduce via 16KB LDS; wave w finalizes q-group w -> Part[..][sp].
__global__ __launch_bounds__(256) void attn_mfma4_kernel(
    const u16* __restrict__ Qh, const u8* __restrict__ Khb,
    const u8* __restrict__ Vtb, float* __restrict__ Part)
{
    __shared__ __align__(16) float Lr[4][4][64][4];   // [wave][qg][lane][4]
    const int bh = blockIdx.x, qt = blockIdx.y, sp = blockIdx.z;
    const int tid = threadIdx.x, w = tid >> 6, l = tid & 63;
    const int g = l >> 4, ql = l & 15;

    // Q fragments (B operand) for the block's 4 q-groups
    s8v bq[4];
    #pragma unroll
    for (int qg = 0; qg < 4; ++qg)
        bq[qg] = *(const s8v*)(Qh + ((size_t)(bh * 2048 + qt * 64 + qg * 16 + ql)) * 16
                               + (g >> 1) * 8);

    const size_t kvoff = (size_t)bh * 65536 + sp * 32768 + w * 8192;
    const u8* kbase = Khb + kvoff + ql * 32 + (g & 1) * 16;
    const u8* vbase = Vtb + kvoff + ql * 32 + g * 8;

    fx4 acc0 = {0.f, 0.f, 0.f, 0.f}, acc1 = acc0, acc2 = acc0, acc3 = acc0;
    const fx4 zf = {0.f, 0.f, 0.f, 0.f};

    #pragma unroll
    for (int seg = 0; seg < 16; ++seg) {              // 16 x 16 keys = 256 keys
        const int off = seg * 512;
        const s8v ak = *(const s8v*)(kbase + off);
        const s4v av = *(const s4v*)(vbase + off);
        #pragma unroll
        for (int qg = 0; qg < 4; ++qg) {
            fx4 s = __builtin_amdgcn_mfma_f32_16x16x32_bf16(ak, bq[qg], zf, 0, 0, 0);
            const float p0 = EXP2(s[0]), p1 = EXP2(s[1]);
            const float p2 = EXP2(s[2]), p3 = EXP2(s[3]);
            union { int i[2]; s4v v; } bp;
            bp.i[0] = pack2bf(p0, p1);
            bp.i[1] = pack2bf(p2, p3);
            fx4& acc = (qg == 0) ? acc0 : (qg == 1) ? acc1 : (qg == 2) ? acc2 : acc3;
            acc = mfma16(av, bp.v, acc);
        }
    }

    // cross-wave reduction over key-quarters
    *(fx4*)&Lr[w][0][l][0] = acc0;
    *(fx4*)&Lr[w][1][l][0] = acc1;
    *(fx4*)&Lr[w][2][l][0] = acc2;
    *(fx4*)&Lr[w][3][l][0] = acc3;
    __syncthreads();
    fx4 fin = {0.f, 0.f, 0.f, 0.f};
    #pragma unroll
    for (int wp = 0; wp < 4; ++wp) {
        const fx4 v = *(const fx4*)&Lr[wp][w][l][0];
        fin[0] += v[0]; fin[1] += v[1]; fin[2] += v[2]; fin[3] += v[3];
    }

    // wave w owns q-group w: rows d=4g+r (g<2); denominator = row 8 (g==2, reg 0)
    const int qglob = qt * 64 + w * 16 + ql;
    float* pp = Part + ((size_t)(bh * 2048 + qglob)) * 24 + sp * 12;
    if (g < 2) {
        const float4 o = {fin[0], fin[1], fin[2], fin[3]};
        *(float4*)(pp + g * 4) = o;
    } else if (g == 2) {
        pp[8] = fin[0];
    }
}

// ---------------- combine split partials ----------------
__global__ __launch_bounds__(256) void attn_combine2_kernel(
    const float* __restrict__ Part, float* __restrict__ M)
{
    const int idx = blockIdx.x * 256 + threadIdx.x;   // 65536 = bh*2048 + q
    const float* pp = Part + (size_t)idx * 24;
    const float inv = 1.0f / (pp[8] + pp[20]);
    float o[8];
    #pragma unroll
    for (int d = 0; d < 8; ++d) o[d] = (pp[d] + pp[12 + d]) * inv;
    const int bh = idx >> 11, q = idx & 2047;
    const int b = bh >> 3, h = bh & 7;
    float* op = M + ((size_t)(b * 2048 + q)) * 64 + h * 8;
    const float4 o0 = {o[0], o[1], o[2], o[3]};
    const float4 o1 = {o[4], o[5], o[6], o[7]};
    *(float4*)op = o0;
    *(float4*)(op + 4) = o1;
}

// ---------------- proj64: mode 0 -> stage-2 Qh/Kh/Vt buffers; mode 1 -> plain f32 out ----------------
// q1 reshape: p-row rr, col c -> bh=bi*8+(rr>>8), key=(rr&255)*8+(c>>3), d=c&7
__global__ __launch_bounds__(64) void proj64_kernel(
    const float* __restrict__ X, const float* __restrict__ W,
    const float* __restrict__ bias,
    u16* __restrict__ Qh, u16* __restrict__ Kh, u16* __restrict__ Vt,
    float* __restrict__ Out, int mode)
{
    __shared__ __align__(16) float xsT[64 * 12];
    const int row0 = blockIdx.x * 8;
    const int c = threadIdx.x;
    #pragma unroll
    for (int r = 0; r < 8; ++r)
        xsT[c * 12 + r] = X[(size_t)(row0 + r) * 64 + c];
    __syncthreads();
    const float bc = bias[c];
    float acc[8];
    #pragma unroll
    for (int r = 0; r < 8; ++r) acc[r] = bc;
    #pragma unroll 4
    for (int k = 0; k < 64; ++k) {
        const float w = W[k * 64 + c];
        const float4 x0 = *(const float4*)&xsT[k * 12];
        const float4 x1 = *(const float4*)&xsT[k * 12 + 4];
        acc[0] = fmaf(x0.x, w, acc[0]);
        acc[1] = fmaf(x0.y, w, acc[1]);
        acc[2] = fmaf(x0.z, w, acc[2]);
        acc[3] = fmaf(x0.w, w, acc[3]);
        acc[4] = fmaf(x1.x, w, acc[4]);
        acc[5] = fmaf(x1.y, w, acc[5]);
        acc[6] = fmaf(x1.z, w, acc[6]);
        acc[7] = fmaf(x1.w, w, acc[7]);
    }
    if (mode == 0) {
        #pragma unroll
        for (int r = 0; r < 8; ++r) {
            const int R = row0 + r;
            const int bi = R >> 11, rr = R & 2047;
            const int bh = bi * 8 + (rr >> 8);
            const int key = (rr & 255) * 8 + (c >> 3);
            const int d = c & 7;
            const int kg = key >> 4, kr = key & 15;
            const float p = acc[r];
            const float qs = p * QK_SCALE;
            const u16 qh = f2bf(qs);
            const u16 qlo = f2bf(qs - bf2f(qh));
            const u16 kh = f2bf(p);
            const u16 kl = f2bf(p - bf2f(kh));
            u16* qp = Qh + ((size_t)(bh * 2048 + key)) * 16 + d;
            qp[0] = qh; qp[8] = qlo;
            u16* kp = Kh + ((size_t)(bh * 128 + kg) * 16 + kr) * 16 + d;
            kp[0] = kh; kp[8] = kl;
            Vt[((size_t)(bh * 128 + kg) * 16 + d) * 16 + kr] = f2bf(p);
        }
    } else {
        #pragma unroll
        for (int r = 0; r < 8; ++r)
            Out[(size_t)(row0 + r) * 64 + c] = acc[r];
    }
}

extern "C" void kernel_launch(void* const* d_in, const int* in_sizes, int n_in,
                              void* d_out, int out_size, void* d_ws, size_t ws_size,
                              hipStream_t stream) {
    const float* x    = (const float*)d_in[0];
    const float* Wqkv = (const float*)d_in[1];
    const float* bqkv = (const float*)d_in[2];
    const float* W1   = (const float*)d_in[3];
    const float* b1   = (const float*)d_in[4];
    float* out = (float*)d_out;
    u8* w8 = (u8*)d_ws;

    // byte layout (20 MiB total)
    u16*   Qh0  = (u16*)(w8);                       // 2 MiB
    u16*   Kh0  = (u16*)(w8 + (2u << 20));          // 2 MiB
    u16*   Vt0  = (u16*)(w8 + (4u << 20));          // 2 MiB
    u16*   Vt1  = (u16*)(w8 + (6u << 20));          // 2 MiB (adjacent to Vt0 for init)
    u16*   Qh1  = (u16*)(w8 + (8u << 20));          // 2 MiB
    u16*   Kh1  = (u16*)(w8 + (10u << 20));         // 2 MiB
    float* Part = (float*)(w8 + (12u << 20));       // 6 MiB
    float* M1   = (float*)(w8 + (18u << 20));       // 2 MiB
    float* M2   = (float*)(w8);                     // overlays Qh0 (dead by then)

    init_vt_kernel<<<2048, 256, 0, stream>>>((u32*)Vt0);  // covers Vt0 and Vt1
    qkv_proj_kernel<<<1024, 192, 0, stream>>>(x, Wqkv, bqkv, Qh0, Kh0, Vt0);
    attn_mfma4_kernel<<<dim3(32, 32, 2), 256, 0, stream>>>(Qh0, (const u8*)Kh0, (const u8*)Vt0, Part);
    attn_combine2_kernel<<<256, 256, 0, stream>>>(Part, M1);
    proj64_kernel<<<1024, 64, 0, stream>>>(M1, W1, b1, Qh1, Kh1, Vt1, nullptr, 0);
    attn_mfma4_kernel<<<dim3(32, 32, 2), 256, 0, stream>>>(Qh1, (const u8*)Kh1, (const u8*)Vt1, Part);
    attn_combine2_kernel<<<256, 256, 0, stream>>>(Part, M2);
    proj64_kernel<<<1024, 64, 0, stream>>>(M2, W1, b1, nullptr, nullptr, nullptr, out, 1);
}

// Round 8
// 72.955 us; speedup vs baseline: 1.3078x; 1.1825x over previous
//
#include <hip/hip_runtime.h>

typedef __attribute__((ext_vector_type(8))) short s8v;
typedef __attribute__((ext_vector_type(4))) short s4v;
typedef __attribute__((ext_vector_type(4))) float fx4;
typedef unsigned short u16;
typedef unsigned int u32;
typedef unsigned char u8;

#define QK_SCALE 0.1803368801111204f  /* 0.125 * log2(e) */

#if __has_builtin(__builtin_amdgcn_exp2f)
#define EXP2(x) __builtin_amdgcn_exp2f(x)
#else
#define EXP2(x) exp2f(x)
#endif

static __device__ __forceinline__ u16 f2bf(float f) {
    u32 u = __float_as_uint(f);
    u += 0x7fffu + ((u >> 16) & 1u);
    return (u16)(u >> 16);
}
static __device__ __forceinline__ float bf2f(u16 h) {
    return __uint_as_float(((u32)h) << 16);
}
// truncate-pack two f32 -> two bf16 in one v_perm (softmax cancels the common bias)
static __device__ __forceinline__ int packtrunc(float a, float b) {
    return (int)__builtin_amdgcn_perm(__float_as_uint(b), __float_as_uint(a), 0x07060302u);
}

static __device__ __forceinline__ fx4 mfma16(s4v a, s4v b, fx4 c) {
#if __has_builtin(__builtin_amdgcn_mfma_f32_16x16x16bf16_1k)
    return __builtin_amdgcn_mfma_f32_16x16x16bf16_1k(a, b, c, 0, 0, 0);
#else
    asm("v_mfma_f32_16x16x16_bf16 %0, %1, %2, %3" : "=v"(c) : "v"(a), "v"(b), "v"(c));
    return c;
#endif
}

// ---------------- K1: qkv proj -> Qh (scaled hi/lo), Kh (hi/lo), Vt (transposed bf16) ----------------
// Also initializes the static V^T rows (d=8 ones, d=9..15 zeros) for Vt0 AND Vt1
// (VtBoth = Vt0 base; Vt1 is contiguous after Vt0). Region = one (buf,bh,kg): 128 words;
// static part at word 64: 8 ones-pairs then 56 zeros.
__global__ __launch_bounds__(192) void qkv_proj_kernel(
    const float* __restrict__ X, const float* __restrict__ W,
    const float* __restrict__ bias,
    u16* __restrict__ Qh, u16* __restrict__ Kh, u16* __restrict__ Vt,
    u32* __restrict__ VtBoth)
{
    // static Vt init: 2*32*128 regions * 64 words = 524288 words over 196608 threads
    {
        const int gt = blockIdx.x * 192 + threadIdx.x;
        #pragma unroll
        for (int i = 0; i < 3; ++i) {
            const int idx = gt + i * 196608;
            if (idx < 524288) {
                const int region = idx >> 6, word = idx & 63;
                VtBoth[region * 128 + 64 + word] = (word < 8) ? 0x3f803f80u : 0u;
            }
        }
    }
    __shared__ __align__(16) float xsT[64 * 12];
    const int row0 = blockIdx.x * 8;
    const int t = threadIdx.x;
    if (t < 64) {
        #pragma unroll
        for (int r = 0; r < 8; ++r)
            xsT[t * 12 + r] = X[(size_t)(row0 + r) * 64 + t];
    }
    __syncthreads();
    const int j = t;
    const float bj = bias[j];
    float acc[8];
    #pragma unroll
    for (int r = 0; r < 8; ++r) acc[r] = bj;
    #pragma unroll 4
    for (int k = 0; k < 64; ++k) {
        const float w = W[k * 192 + j];
        const float4 x0 = *(const float4*)&xsT[k * 12];
        const float4 x1 = *(const float4*)&xsT[k * 12 + 4];
        acc[0] = fmaf(x0.x, w, acc[0]);
        acc[1] = fmaf(x0.y, w, acc[1]);
        acc[2] = fmaf(x0.z, w, acc[2]);
        acc[3] = fmaf(x0.w, w, acc[3]);
        acc[4] = fmaf(x1.x, w, acc[4]);
        acc[5] = fmaf(x1.y, w, acc[5]);
        acc[6] = fmaf(x1.z, w, acc[6]);
        acc[7] = fmaf(x1.w, w, acc[7]);
    }
    const int c = j & 63;
    const int h = c >> 3, d = c & 7;
    #pragma unroll
    for (int r = 0; r < 8; ++r) {
        const int R = row0 + r;
        const int bi = R >> 11, i = R & 2047;
        const int bh = bi * 8 + h;
        const float v = acc[r];
        if (j < 64) {
            const float qs = v * QK_SCALE;
            const u16 hh = f2bf(qs);
            const u16 ll = f2bf(qs - bf2f(hh));
            u16* qp = Qh + ((size_t)(bh * 2048 + i)) * 16 + d;
            qp[0] = hh; qp[8] = ll;
        } else if (j < 128) {
            const u16 hh = f2bf(v);
            const u16 ll = f2bf(v - bf2f(hh));
            u16* kp = Kh + ((size_t)(bh * 128 + (i >> 4)) * 16 + (i & 15)) * 16 + d;
            kp[0] = hh; kp[8] = ll;
        } else {
            Vt[((size_t)(bh * 128 + (i >> 4)) * 16 + d) * 16 + (i & 15)] = f2bf(v);
        }
    }
}

// ---------------- MFMA attention v5: register pipeline, wave = key-quarter ----------------
// grid (bh=32, qt=32, sp=2), block 256 = 4 waves. Wave w: keys [w*256,(w+1)*256) for all 64 q.
// Rolled seg loop (8 x 2 segs), 2-seg-deep register prefetch (overreads <=1KB into
// adjacent ws regions - valid memory, values unused). launch_bounds(256,4): >=4 waves/SIMD.
// QK: mfma_16x16x32: A lane(key=l&15,g=l>>4) = K hi(g even)/lo(g odd); B=Q[qhi,qhi,qlo,qlo].
// C: col=q=l&15, row=key=4g+r. P=exp2(S) -> packtrunc = B-frag of 16x16x16 (k=4g+j).
// A_V rows: d=0..7 V^T, 8=ones (denominator). Cross-wave key reduce via 16KB LDS.
__global__ __launch_bounds__(256, 4) void attn_mfma5_kernel(
    const u16* __restrict__ Qh, const u8* __restrict__ Khb,
    const u8* __restrict__ Vtb, float* __restrict__ Part)
{
    __shared__ __align__(16) float Lr[4][4][64][4];   // [wave][qg][lane][4]
    const int bh = blockIdx.x, qt = blockIdx.y, sp = blockIdx.z;
    const int tid = threadIdx.x, w = tid >> 6, l = tid & 63;
    const int g = l >> 4, ql = l & 15;

    s8v bq[4];
    #pragma unroll
    for (int qg = 0; qg < 4; ++qg)
        bq[qg] = *(const s8v*)(Qh + ((size_t)(bh * 2048 + qt * 64 + qg * 16 + ql)) * 16
                               + (g >> 1) * 8);

    const size_t kvoff = (size_t)bh * 65536 + sp * 32768 + w * 8192;
    const u8* kptr = Khb + kvoff + ql * 32 + (g & 1) * 16;
    const u8* vptr = Vtb + kvoff + ql * 32 + g * 8;

    fx4 acc0 = {0.f, 0.f, 0.f, 0.f}, acc1 = acc0, acc2 = acc0, acc3 = acc0;
    const fx4 zf = {0.f, 0.f, 0.f, 0.f};

    s8v k0 = *(const s8v*)(kptr);
    s8v k1 = *(const s8v*)(kptr + 512);
    s4v v0 = *(const s4v*)(vptr);
    s4v v1 = *(const s4v*)(vptr + 512);

#define QK_COMPUTE(KA, VA)                                                      \
    {                                                                           \
        _Pragma("unroll")                                                       \
        for (int qg = 0; qg < 4; ++qg) {                                        \
            fx4 s = __builtin_amdgcn_mfma_f32_16x16x32_bf16(KA, bq[qg], zf, 0, 0, 0); \
            const float e0 = EXP2(s[0]), e1 = EXP2(s[1]);                       \
            const float e2 = EXP2(s[2]), e3 = EXP2(s[3]);                       \
            union { int i[2]; s4v v; } bp;                                      \
            bp.i[0] = packtrunc(e0, e1);                                        \
            bp.i[1] = packtrunc(e2, e3);                                        \
            fx4& acc = (qg == 0) ? acc0 : (qg == 1) ? acc1 : (qg == 2) ? acc2 : acc3; \
            acc = mfma16(VA, bp.v, acc);                                        \
        }                                                                       \
    }

    #pragma unroll 1
    for (int seg = 0; seg < 16; seg += 2) {
        const s8v k2 = *(const s8v*)(kptr + (seg + 2) * 512);
        const s4v v2 = *(const s4v*)(vptr + (seg + 2) * 512);
        const s8v k3 = *(const s8v*)(kptr + (seg + 3) * 512);
        const s4v v3 = *(const s4v*)(vptr + (seg + 3) * 512);
        QK_COMPUTE(k0, v0);
        QK_COMPUTE(k1, v1);
        k0 = k2; v0 = v2; k1 = k3; v1 = v3;
    }
#undef QK_COMPUTE

    // cross-wave reduction over key-quarters
    *(fx4*)&Lr[w][0][l][0] = acc0;
    *(fx4*)&Lr[w][1][l][0] = acc1;
    *(fx4*)&Lr[w][2][l][0] = acc2;
    *(fx4*)&Lr[w][3][l][0] = acc3;
    __syncthreads();
    fx4 fin = {0.f, 0.f, 0.f, 0.f};
    #pragma unroll
    for (int wp = 0; wp < 4; ++wp) {
        const fx4 v = *(const fx4*)&Lr[wp][w][l][0];
        fin[0] += v[0]; fin[1] += v[1]; fin[2] += v[2]; fin[3] += v[3];
    }

    // wave w owns q-group w: rows d=4g+r (g<2); denominator = row 8 (g==2, reg 0)
    const int qglob = qt * 64 + w * 16 + ql;
    float* pp = Part + ((size_t)(bh * 2048 + qglob)) * 24 + sp * 12;
    if (g < 2) {
        const float4 o = {fin[0], fin[1], fin[2], fin[3]};
        *(float4*)(pp + g * 4) = o;
    } else if (g == 2) {
        pp[8] = fin[0];
    }
}

// ---------------- combine split partials ----------------
__global__ __launch_bounds__(256) void attn_combine2_kernel(
    const float* __restrict__ Part, float* __restrict__ M)
{
    const int idx = blockIdx.x * 256 + threadIdx.x;   // 65536 = bh*2048 + q
    const float* pp = Part + (size_t)idx * 24;
    const float inv = 1.0f / (pp[8] + pp[20]);
    float o[8];
    #pragma unroll
    for (int d = 0; d < 8; ++d) o[d] = (pp[d] + pp[12 + d]) * inv;
    const int bh = idx >> 11, q = idx & 2047;
    const int b = bh >> 3, h = bh & 7;
    float* op = M + ((size_t)(b * 2048 + q)) * 64 + h * 8;
    const float4 o0 = {o[0], o[1], o[2], o[3]};
    const float4 o1 = {o[4], o[5], o[6], o[7]};
    *(float4*)op = o0;
    *(float4*)(op + 4) = o1;
}

// ---------------- proj64: mode 0 -> stage-2 Qh/Kh/Vt buffers; mode 1 -> plain f32 out ----------------
// q1 reshape: p-row rr, col c -> bh=bi*8+(rr>>8), key=(rr&255)*8+(c>>3), d=c&7
__global__ __launch_bounds__(64) void proj64_kernel(
    const float* __restrict__ X, const float* __restrict__ W,
    const float* __restrict__ bias,
    u16* __restrict__ Qh, u16* __restrict__ Kh, u16* __restrict__ Vt,
    float* __restrict__ Out, int mode)
{
    __shared__ __align__(16) float xsT[64 * 12];
    const int row0 = blockIdx.x * 8;
    const int c = threadIdx.x;
    #pragma unroll
    for (int r = 0; r < 8; ++r)
        xsT[c * 12 + r] = X[(size_t)(row0 + r) * 64 + c];
    __syncthreads();
    const float bc = bias[c];
    float acc[8];
    #pragma unroll
    for (int r = 0; r < 8; ++r) acc[r] = bc;
    #pragma unroll 4
    for (int k = 0; k < 64; ++k) {
        const float w = W[k * 64 + c];
        const float4 x0 = *(const float4*)&xsT[k * 12];
        const float4 x1 = *(const float4*)&xsT[k * 12 + 4];
        acc[0] = fmaf(x0.x, w, acc[0]);
        acc[1] = fmaf(x0.y, w, acc[1]);
        acc[2] = fmaf(x0.z, w, acc[2]);
        acc[3] = fmaf(x0.w, w, acc[3]);
        acc[4] = fmaf(x1.x, w, acc[4]);
        acc[5] = fmaf(x1.y, w, acc[5]);
        acc[6] = fmaf(x1.z, w, acc[6]);
        acc[7] = fmaf(x1.w, w, acc[7]);
    }
    if (mode == 0) {
        #pragma unroll
        for (int r = 0; r < 8; ++r) {
            const int R = row0 + r;
            const int bi = R >> 11, rr = R & 2047;
            const int bh = bi * 8 + (rr >> 8);
            const int key = (rr & 255) * 8 + (c >> 3);
            const int d = c & 7;
            const int kg = key >> 4, kr = key & 15;
            const float p = acc[r];
            const float qs = p * QK_SCALE;
            const u16 qh = f2bf(qs);
            const u16 qlo = f2bf(qs - bf2f(qh));
            const u16 kh = f2bf(p);
            const u16 kl = f2bf(p - bf2f(kh));
            u16* qp = Qh + ((size_t)(bh * 2048 + key)) * 16 + d;
            qp[0] = qh; qp[8] = qlo;
            u16* kp = Kh + ((size_t)(bh * 128 + kg) * 16 + kr) * 16 + d;
            kp[0] = kh; kp[8] = kl;
            Vt[((size_t)(bh * 128 + kg) * 16 + d) * 16 + kr] = f2bf(p);
        }
    } else {
        #pragma unroll
        for (int r = 0; r < 8; ++r)
            Out[(size_t)(row0 + r) * 64 + c] = acc[r];
    }
}

extern "C" void kernel_launch(void* const* d_in, const int* in_sizes, int n_in,
                              void* d_out, int out_size, void* d_ws, size_t ws_size,
                              hipStream_t stream) {
    const float* x    = (const float*)d_in[0];
    const float* Wqkv = (const float*)d_in[1];
    const float* bqkv = (const float*)d_in[2];
    const float* W1   = (const float*)d_in[3];
    const float* b1   = (const float*)d_in[4];
    float* out = (float*)d_out;
    u8* w8 = (u8*)d_ws;

    // byte layout (20 MiB total)
    u16*   Qh0  = (u16*)(w8);                       // 2 MiB
    u16*   Kh0  = (u16*)(w8 + (2u << 20));          // 2 MiB
    u16*   Vt0  = (u16*)(w8 + (4u << 20));          // 2 MiB
    u16*   Vt1  = (u16*)(w8 + (6u << 20));          // 2 MiB (adjacent to Vt0 for init)
    u16*   Qh1  = (u16*)(w8 + (8u << 20));          // 2 MiB
    u16*   Kh1  = (u16*)(w8 + (10u << 20));         // 2 MiB
    float* Part = (float*)(w8 + (12u << 20));       // 6 MiB
    float* M1   = (float*)(w8 + (18u << 20));       // 2 MiB
    float* M2   = (float*)(w8);                     // overlays Qh0 (dead by then)

    qkv_proj_kernel<<<1024, 192, 0, stream>>>(x, Wqkv, bqkv, Qh0, Kh0, Vt0, (u32*)Vt0);
    attn_mfma5_kernel<<<dim3(32, 32, 2), 256, 0, stream>>>(Qh0, (const u8*)Kh0, (const u8*)Vt0, Part);
    attn_combine2_kernel<<<256, 256, 0, stream>>>(Part, M1);
    proj64_kernel<<<1024, 64, 0, stream>>>(M1, W1, b1, Qh1, Kh1, Vt1, nullptr, 0);
    attn_mfma5_kernel<<<dim3(32, 32, 2), 256, 0, stream>>>(Qh1, (const u8*)Kh1, (const u8*)Vt1, Part);
    attn_combine2_kernel<<<256, 256, 0, stream>>>(Part, M2);
    proj64_kernel<<<1024, 64, 0, stream>>>(M2, W1, b1, nullptr, nullptr, nullptr, out, 1);
}

// Round 9
// 72.935 us; speedup vs baseline: 1.3082x; 1.0003x over previous
//
#include <hip/hip_runtime.h>

typedef __attribute__((ext_vector_type(8))) short s8v;
typedef __attribute__((ext_vector_type(4))) short s4v;
typedef __attribute__((ext_vector_type(4))) float fx4;
typedef unsigned short u16;
typedef unsigned int u32;
typedef unsigned char u8;

#define QK_SCALE 0.1803368801111204f  /* 0.125 * log2(e) */

#if __has_builtin(__builtin_amdgcn_exp2f)
#define EXP2(x) __builtin_amdgcn_exp2f(x)
#else
#define EXP2(x) exp2f(x)
#endif

static __device__ __forceinline__ u16 f2bf(float f) {
    u32 u = __float_as_uint(f);
    u += 0x7fffu + ((u >> 16) & 1u);
    return (u16)(u >> 16);
}
static __device__ __forceinline__ float bf2f(u16 h) {
    return __uint_as_float(((u32)h) << 16);
}
// truncate-pack two f32 -> two bf16 in one v_perm (softmax cancels the common bias)
static __device__ __forceinline__ int packtrunc(float a, float b) {
    return (int)__builtin_amdgcn_perm(__float_as_uint(b), __float_as_uint(a), 0x07060302u);
}

static __device__ __forceinline__ fx4 mfma16(s4v a, s4v b, fx4 c) {
#if __has_builtin(__builtin_amdgcn_mfma_f32_16x16x16bf16_1k)
    return __builtin_amdgcn_mfma_f32_16x16x16bf16_1k(a, b, c, 0, 0, 0);
#else
    asm("v_mfma_f32_16x16x16_bf16 %0, %1, %2, %3" : "=v"(c) : "v"(a), "v"(b), "v"(c));
    return c;
#endif
}

// ---------------- K1: qkv proj -> Qh (scaled hi/lo), Kh (hi/lo), Vt (transposed bf16) ----------------
// Also initializes the static V^T rows (d=8 ones, d=9..15 zeros) for Vt0 AND Vt1.
__global__ __launch_bounds__(192) void qkv_proj_kernel(
    const float* __restrict__ X, const float* __restrict__ W,
    const float* __restrict__ bias,
    u16* __restrict__ Qh, u16* __restrict__ Kh, u16* __restrict__ Vt,
    u32* __restrict__ VtBoth)
{
    {
        const int gt = blockIdx.x * 192 + threadIdx.x;
        #pragma unroll
        for (int i = 0; i < 3; ++i) {
            const int idx = gt + i * 196608;
            if (idx < 524288) {
                const int region = idx >> 6, word = idx & 63;
                VtBoth[region * 128 + 64 + word] = (word < 8) ? 0x3f803f80u : 0u;
            }
        }
    }
    __shared__ __align__(16) float xsT[64 * 12];
    const int row0 = blockIdx.x * 8;
    const int t = threadIdx.x;
    if (t < 64) {
        #pragma unroll
        for (int r = 0; r < 8; ++r)
            xsT[t * 12 + r] = X[(size_t)(row0 + r) * 64 + t];
    }
    __syncthreads();
    const int j = t;
    const float bj = bias[j];
    float acc[8];
    #pragma unroll
    for (int r = 0; r < 8; ++r) acc[r] = bj;
    #pragma unroll 4
    for (int k = 0; k < 64; ++k) {
        const float w = W[k * 192 + j];
        const float4 x0 = *(const float4*)&xsT[k * 12];
        const float4 x1 = *(const float4*)&xsT[k * 12 + 4];
        acc[0] = fmaf(x0.x, w, acc[0]);
        acc[1] = fmaf(x0.y, w, acc[1]);
        acc[2] = fmaf(x0.z, w, acc[2]);
        acc[3] = fmaf(x0.w, w, acc[3]);
        acc[4] = fmaf(x1.x, w, acc[4]);
        acc[5] = fmaf(x1.y, w, acc[5]);
        acc[6] = fmaf(x1.z, w, acc[6]);
        acc[7] = fmaf(x1.w, w, acc[7]);
    }
    const int c = j & 63;
    const int h = c >> 3, d = c & 7;
    #pragma unroll
    for (int r = 0; r < 8; ++r) {
        const int R = row0 + r;
        const int bi = R >> 11, i = R & 2047;
        const int bh = bi * 8 + h;
        const float v = acc[r];
        if (j < 64) {
            const float qs = v * QK_SCALE;
            const u16 hh = f2bf(qs);
            const u16 ll = f2bf(qs - bf2f(hh));
            u16* qp = Qh + ((size_t)(bh * 2048 + i)) * 16 + d;
            qp[0] = hh; qp[8] = ll;
        } else if (j < 128) {
            const u16 hh = f2bf(v);
            const u16 ll = f2bf(v - bf2f(hh));
            u16* kp = Kh + ((size_t)(bh * 128 + (i >> 4)) * 16 + (i & 15)) * 16 + d;
            kp[0] = hh; kp[8] = ll;
        } else {
            Vt[((size_t)(bh * 128 + (i >> 4)) * 16 + d) * 16 + (i & 15)] = f2bf(v);
        }
    }
}

// ---------------- MFMA attention v6: wave = key-quarter x 128 q (8 chains) ----------------
// grid (bh=32, qt=16, sp=2) = 1024 blocks = exactly 4 blocks/CU, single round.
// Block: 128 q x 1024 keys. Wave w: keys [w*256,(w+1)*256) for all 128 q (8 qg chains).
// Per-seg issue ~220cyc with 2-seg prefetch -> ~440cyc lookahead >> L2 latency.
// QK: mfma_16x16x32: A lane(key=l&15,g=l>>4) = K hi(g even)/lo(g odd); B=Q[qhi,qhi,qlo,qlo].
// C: col=q=l&15, row=key=4g+r. P=exp2(S) -> packtrunc = B-frag of 16x16x16 (k=4g+j).
// A_V rows: d=0..7 V^T, 8=ones (denominator). Cross-wave key reduce via 32KB LDS.
__global__ __launch_bounds__(256, 4) void attn_mfma6_kernel(
    const u16* __restrict__ Qh, const u8* __restrict__ Khb,
    const u8* __restrict__ Vtb, float* __restrict__ Part)
{
    __shared__ __align__(16) float Lr[4][8][64][4];   // [wave][qg][lane][4] = 32KB
    const int bh = blockIdx.x, qt = blockIdx.y, sp = blockIdx.z;
    const int tid = threadIdx.x, w = tid >> 6, l = tid & 63;
    const int g = l >> 4, ql = l & 15;

    s8v bq[8];
    #pragma unroll
    for (int qg = 0; qg < 8; ++qg)
        bq[qg] = *(const s8v*)(Qh + ((size_t)(bh * 2048 + qt * 128 + qg * 16 + ql)) * 16
                               + (g >> 1) * 8);

    const size_t kvoff = (size_t)bh * 65536 + sp * 32768 + w * 8192;
    const u8* kptr = Khb + kvoff + ql * 32 + (g & 1) * 16;
    const u8* vptr = Vtb + kvoff + ql * 32 + g * 8;

    fx4 acc[8];
    #pragma unroll
    for (int qg = 0; qg < 8; ++qg) acc[qg] = fx4{0.f, 0.f, 0.f, 0.f};
    const fx4 zf = {0.f, 0.f, 0.f, 0.f};

    s8v k0 = *(const s8v*)(kptr);
    s8v k1 = *(const s8v*)(kptr + 512);
    s4v v0 = *(const s4v*)(vptr);
    s4v v1 = *(const s4v*)(vptr + 512);

#define QK_COMPUTE(KA, VA)                                                      \
    {                                                                           \
        _Pragma("unroll")                                                       \
        for (int qg = 0; qg < 8; ++qg) {                                        \
            fx4 s = __builtin_amdgcn_mfma_f32_16x16x32_bf16(KA, bq[qg], zf, 0, 0, 0); \
            const float e0 = EXP2(s[0]), e1 = EXP2(s[1]);                       \
            const float e2 = EXP2(s[2]), e3 = EXP2(s[3]);                       \
            union { int i[2]; s4v v; } bp;                                      \
            bp.i[0] = packtrunc(e0, e1);                                        \
            bp.i[1] = packtrunc(e2, e3);                                        \
            acc[qg] = mfma16(VA, bp.v, acc[qg]);                                \
        }                                                                       \
    }

    #pragma unroll 1
    for (int seg = 0; seg < 16; seg += 2) {
        const s8v k2 = *(const s8v*)(kptr + (seg + 2) * 512);
        const s4v v2 = *(const s4v*)(vptr + (seg + 2) * 512);
        const s8v k3 = *(const s8v*)(kptr + (seg + 3) * 512);
        const s4v v3 = *(const s4v*)(vptr + (seg + 3) * 512);
        QK_COMPUTE(k0, v0);
        QK_COMPUTE(k1, v1);
        k0 = k2; v0 = v2; k1 = k3; v1 = v3;
    }
#undef QK_COMPUTE

    // cross-wave reduction over key-quarters
    #pragma unroll
    for (int qg = 0; qg < 8; ++qg)
        *(fx4*)&Lr[w][qg][l][0] = acc[qg];
    __syncthreads();

    #pragma unroll
    for (int qq = 0; qq < 2; ++qq) {
        const int qg = w * 2 + qq;
        fx4 fin = {0.f, 0.f, 0.f, 0.f};
        #pragma unroll
        for (int wp = 0; wp < 4; ++wp) {
            const fx4 v = *(const fx4*)&Lr[wp][qg][l][0];
            fin[0] += v[0]; fin[1] += v[1]; fin[2] += v[2]; fin[3] += v[3];
        }
        const int qglob = qt * 128 + qg * 16 + ql;
        float* pp = Part + ((size_t)(bh * 2048 + qglob)) * 24 + sp * 12;
        if (g < 2) {
            const float4 o = {fin[0], fin[1], fin[2], fin[3]};
            *(float4*)(pp + g * 4) = o;
        } else if (g == 2) {
            pp[8] = fin[0];
        }
    }
}

// ---------------- combine split partials ----------------
__global__ __launch_bounds__(256) void attn_combine2_kernel(
    const float* __restrict__ Part, float* __restrict__ M)
{
    const int idx = blockIdx.x * 256 + threadIdx.x;   // 65536 = bh*2048 + q
    const float* pp = Part + (size_t)idx * 24;
    const float inv = 1.0f / (pp[8] + pp[20]);
    float o[8];
    #pragma unroll
    for (int d = 0; d < 8; ++d) o[d] = (pp[d] + pp[12 + d]) * inv;
    const int bh = idx >> 11, q = idx & 2047;
    const int b = bh >> 3, h = bh & 7;
    float* op = M + ((size_t)(b * 2048 + q)) * 64 + h * 8;
    const float4 o0 = {o[0], o[1], o[2], o[3]};
    const float4 o1 = {o[4], o[5], o[6], o[7]};
    *(float4*)op = o0;
    *(float4*)(op + 4) = o1;
}

// ---------------- proj64: mode 0 -> stage-2 Qh/Kh/Vt buffers; mode 1 -> plain f32 out ----------------
// q1 reshape: p-row rr, col c -> bh=bi*8+(rr>>8), key=(rr&255)*8+(c>>3), d=c&7
__global__ __launch_bounds__(64) void proj64_kernel(
    const float* __restrict__ X, const float* __restrict__ W,
    const float* __restrict__ bias,
    u16* __restrict__ Qh, u16* __restrict__ Kh, u16* __restrict__ Vt,
    float* __restrict__ Out, int mode)
{
    __shared__ __align__(16) float xsT[64 * 12];
    const int row0 = blockIdx.x * 8;
    const int c = threadIdx.x;
    #pragma unroll
    for (int r = 0; r < 8; ++r)
        xsT[c * 12 + r] = X[(size_t)(row0 + r) * 64 + c];
    __syncthreads();
    const float bc = bias[c];
    float acc[8];
    #pragma unroll
    for (int r = 0; r < 8; ++r) acc[r] = bc;
    #pragma unroll 4
    for (int k = 0; k < 64; ++k) {
        const float w = W[k * 64 + c];
        const float4 x0 = *(const float4*)&xsT[k * 12];
        const float4 x1 = *(const float4*)&xsT[k * 12 + 4];
        acc[0] = fmaf(x0.x, w, acc[0]);
        acc[1] = fmaf(x0.y, w, acc[1]);
        acc[2] = fmaf(x0.z, w, acc[2]);
        acc[3] = fmaf(x0.w, w, acc[3]);
        acc[4] = fmaf(x1.x, w, acc[4]);
        acc[5] = fmaf(x1.y, w, acc[5]);
        acc[6] = fmaf(x1.z, w, acc[6]);
        acc[7] = fmaf(x1.w, w, acc[7]);
    }
    if (mode == 0) {
        #pragma unroll
        for (int r = 0; r < 8; ++r) {
            const int R = row0 + r;
            const int bi = R >> 11, rr = R & 2047;
            const int bh = bi * 8 + (rr >> 8);
            const int key = (rr & 255) * 8 + (c >> 3);
            const int d = c & 7;
            const int kg = key >> 4, kr = key & 15;
            const float p = acc[r];
            const float qs = p * QK_SCALE;
            const u16 qh = f2bf(qs);
            const u16 qlo = f2bf(qs - bf2f(qh));
            const u16 kh = f2bf(p);
            const u16 kl = f2bf(p - bf2f(kh));
            u16* qp = Qh + ((size_t)(bh * 2048 + key)) * 16 + d;
            qp[0] = qh; qp[8] = qlo;
            u16* kp = Kh + ((size_t)(bh * 128 + kg) * 16 + kr) * 16 + d;
            kp[0] = kh; kp[8] = kl;
            Vt[((size_t)(bh * 128 + kg) * 16 + d) * 16 + kr] = f2bf(p);
        }
    } else {
        #pragma unroll
        for (int r = 0; r < 8; ++r)
            Out[(size_t)(row0 + r) * 64 + c] = acc[r];
    }
}

extern "C" void kernel_launch(void* const* d_in, const int* in_sizes, int n_in,
                              void* d_out, int out_size, void* d_ws, size_t ws_size,
                              hipStream_t stream) {
    const float* x    = (const float*)d_in[0];
    const float* Wqkv = (const float*)d_in[1];
    const float* bqkv = (const float*)d_in[2];
    const float* W1   = (const float*)d_in[3];
    const float* b1   = (const float*)d_in[4];
    float* out = (float*)d_out;
    u8* w8 = (u8*)d_ws;

    // byte layout (20 MiB total)
    u16*   Qh0  = (u16*)(w8);                       // 2 MiB
    u16*   Kh0  = (u16*)(w8 + (2u << 20));          // 2 MiB
    u16*   Vt0  = (u16*)(w8 + (4u << 20));          // 2 MiB
    u16*   Vt1  = (u16*)(w8 + (6u << 20));          // 2 MiB (adjacent to Vt0 for init)
    u16*   Qh1  = (u16*)(w8 + (8u << 20));          // 2 MiB
    u16*   Kh1  = (u16*)(w8 + (10u << 20));         // 2 MiB
    float* Part = (float*)(w8 + (12u << 20));       // 6 MiB
    float* M1   = (float*)(w8 + (18u << 20));       // 2 MiB
    float* M2   = (float*)(w8);                     // overlays Qh0 (dead by then)

    qkv_proj_kernel<<<1024, 192, 0, stream>>>(x, Wqkv, bqkv, Qh0, Kh0, Vt0, (u32*)Vt0);
    attn_mfma6_kernel<<<dim3(32, 16, 2), 256, 0, stream>>>(Qh0, (const u8*)Kh0, (const u8*)Vt0, Part);
    attn_combine2_kernel<<<256, 256, 0, stream>>>(Part, M1);
    proj64_kernel<<<1024, 64, 0, stream>>>(M1, W1, b1, Qh1, Kh1, Vt1, nullptr, 0);
    attn_mfma6_kernel<<<dim3(32, 16, 2), 256, 0, stream>>>(Qh1, (const u8*)Kh1, (const u8*)Vt1, Part);
    attn_combine2_kernel<<<256, 256, 0, stream>>>(Part, M2);
    proj64_kernel<<<1024, 64, 0, stream>>>(M2, W1, b1, nullptr, nullptr, nullptr, out, 1);
}